// Round 1
// baseline (412.684 us; speedup 1.0000x reference)
//
#include <hip/hip_runtime.h>
#include <cstdint>
#include <cstddef>

#define NB 2048
#define TAU 32
#define T0C 96
#define LQ 128      // T0 + tau
#define DD 64
#define DOUT 64
#define KK 16
#define NCOPY 1024

// exact-rounding helpers: prevent fp-contract from fusing mul+add into fma,
// so d2 matches the reference's mul,mul,mul,add,add sequence bit-for-bit.
__device__ __forceinline__ float fmul_exact(float a, float b) {
  float r; asm("v_mul_f32 %0, %1, %2" : "=v"(r) : "v"(a), "v"(b)); return r;
}
__device__ __forceinline__ float fadd_exact(float a, float b) {
  float r; asm("v_add_f32 %0, %1, %2" : "=v"(r) : "v"(a), "v"(b)); return r;
}

__device__ __forceinline__ unsigned long long shfl_xor_u64(unsigned long long v, int mask) {
  int lo = __shfl_xor((int)(unsigned)(v & 0xffffffffULL), mask, 64);
  int hi = __shfl_xor((int)(unsigned)(v >> 32), mask, 64);
  return ((unsigned long long)(unsigned)hi << 32) | (unsigned)lo;
}

__global__ __launch_bounds__(256) void navgcm(
    const float* __restrict__ x, const float* __restrict__ pos_in, const float* __restrict__ rot_in,
    const float* __restrict__ old_x, const float* __restrict__ old_pos, const float* __restrict__ old_rot,
    const float* __restrict__ W_self, const float* __restrict__ W_nbr, const float* __restrict__ bias,
    float* __restrict__ out)
{
  const int tid = threadIdx.x;

  if ((int)blockIdx.x >= NB) {
    // ---------------- copy blocks ----------------
    const int g = (blockIdx.x - NB) * 256 + tid;
    const int nthr = NCOPY * 256;

    // new_x as float4: per b, 2048 f4 (rows 0..95 from old_x, 96..127 from x)
    float4* __restrict__ dnx = (float4*)(out + (size_t)NB * TAU * DOUT);
    const float4* __restrict__ sox = (const float4*)old_x;
    const float4* __restrict__ sx  = (const float4*)x;
    const int NX4 = NB * LQ * DD / 4;  // 4,194,304
    for (int n = g; n < NX4; n += nthr) {
      int b = n >> 11;          // 2048 f4 per batch
      int r = n & 2047;
      int t = r >> 4;
      float4 v = (t < T0C) ? sox[(size_t)b * 2048 + r]
                           : sx[(size_t)b * 512 + (r - T0C * 16)];
      dnx[(size_t)b * 2048 + r] = v;
    }

    // new_pos + new_rot, one row (3+1 floats) per thread
    float* __restrict__ dpos = out + (size_t)NB * TAU * DOUT + (size_t)NB * LQ * DD;
    float* __restrict__ drot = dpos + (size_t)NB * LQ * 3;
    const int NROWS = NB * LQ;  // 262,144
    for (int n = g; n < NROWS; n += nthr) {
      int b = n >> 7, t = n & 127;
      float p0, p1, p2, rr;
      if (t < T0C) {
        const float* s = old_pos + (size_t)n * 3;
        p0 = s[0]; p1 = s[1]; p2 = s[2];
        rr = old_rot[n];
      } else {
        const float* s = pos_in + ((size_t)b * TAU + (t - T0C)) * 3;
        p0 = s[0]; p1 = s[1]; p2 = s[2];
        rr = rot_in[(size_t)b * TAU + (t - T0C)];
      }
      dpos[(size_t)n * 3 + 0] = p0;
      dpos[(size_t)n * 3 + 1] = p1;
      dpos[(size_t)n * 3 + 2] = p2;
      drot[n] = rr;
    }
    return;
  }

  // ---------------- compute blocks (one per batch element) ----------------
  const int b = blockIdx.x;
  const int lane = tid & 63;
  const int wv = tid >> 6;

  __shared__ float px[LQ], py[LQ], pz[LQ], rt[LQ];
  __shared__ float msg[LQ * DOUT];  // 32 KB

  // stage pos/rot (updated view) into LDS
  if (tid < LQ) {
    int t = tid;
    float p0, p1, p2, rr;
    if (t < T0C) {
      const float* s = old_pos + ((size_t)b * LQ + t) * 3;
      p0 = s[0]; p1 = s[1]; p2 = s[2];
      rr = old_rot[(size_t)b * LQ + t];
    } else {
      const float* s = pos_in + ((size_t)b * TAU + (t - T0C)) * 3;
      p0 = s[0]; p1 = s[1]; p2 = s[2];
      rr = rot_in[(size_t)b * TAU + (t - T0C)];
    }
    px[t] = p0; py[t] = p1; pz[t] = p2; rt[t] = rr;
  }

  // W_nbr column for this thread's output dim (o = lane), 68 regs
  float wcol[68];
  #pragma unroll
  for (int c = 0; c < 68; ++c) wcol[c] = W_nbr[c * DOUT + lane];

  __syncthreads();

  // msg[j][o] = h[j] . W_nbr[:,o], rows j = wv + 4k  (wave-uniform row)
  #pragma unroll 2
  for (int k = 0; k < 32; ++k) {
    int j = wv + 4 * k;
    const float4* hr = (j < T0C)
        ? (const float4*)(old_x + ((size_t)b * LQ + j) * DD)
        : (const float4*)(x + ((size_t)b * TAU + (j - T0C)) * DD);
    float acc = 0.f;
    #pragma unroll
    for (int c4 = 0; c4 < 16; ++c4) {
      float4 v = hr[c4];
      acc += v.x * wcol[4 * c4 + 0];
      acc += v.y * wcol[4 * c4 + 1];
      acc += v.z * wcol[4 * c4 + 2];
      acc += v.w * wcol[4 * c4 + 3];
    }
    acc += px[j] * wcol[64] + py[j] * wcol[65] + pz[j] * wcol[66] + rt[j] * wcol[67];
    msg[j * DOUT + lane] = acc;
  }
  __syncthreads();

  // each wave handles 8 queries i = 96 + wv*8 + q
  for (int q = 0; q < 8; ++q) {
    const int i = T0C + wv * 8 + q;
    const float pix = px[i], piy = py[i], piz = pz[i], ri = rt[i];

    // candidate keys: (d2_bits << 32) | j, lexicographic == lax.top_k order
    unsigned long long k0, k1;
    {
      int j = lane;  // j < 96 <= i: always causal
      float dx = pix - px[j], dy = piy - py[j], dz = piz - pz[j];
      float d2 = fadd_exact(fadd_exact(fmul_exact(dx, dx), fmul_exact(dy, dy)),
                            fmul_exact(dz, dz));
      k0 = (d2 <= 1.0f)
         ? ((((unsigned long long)__float_as_uint(d2)) << 32) | (unsigned)j)
         : ~0ULL;
    }
    {
      int j = 64 + lane;
      if (j < i) {
        float dx = pix - px[j], dy = piy - py[j], dz = piz - pz[j];
        float d2 = fadd_exact(fadd_exact(fmul_exact(dx, dx), fmul_exact(dy, dy)),
                              fmul_exact(dz, dz));
        k1 = (d2 <= 1.0f)
           ? ((((unsigned long long)__float_as_uint(d2)) << 32) | (unsigned)j)
           : ~0ULL;
      } else {
        k1 = ~0ULL;
      }
    }

    // extract-min 16 times; accumulate msg row of each winner (ascending order,
    // matching the reference's gather-sum order)
    float agg = 0.f;
    #pragma unroll 1
    for (int s = 0; s < KK; ++s) {
      unsigned long long m = k0 < k1 ? k0 : k1;
      #pragma unroll
      for (int off = 32; off > 0; off >>= 1) {
        unsigned long long o2 = shfl_xor_u64(m, off);
        if (o2 < m) m = o2;
      }
      if (m == ~0ULL) break;  // fewer than 16 valid neighbors (wave-uniform)
      int jw = (int)(m & 0x7f);
      agg += msg[jw * DOUT + lane];
      if (k0 == m) k0 = ~0ULL;
      else if (k1 == m) k1 = ~0ULL;
    }

    // epilogue: out = relu(h[i] . W_self[:,o] + agg + bias[o])
    const float4* xi = (const float4*)(x + ((size_t)b * TAU + (i - T0C)) * DD);
    float acc = bias[lane] + agg;
    #pragma unroll
    for (int c4 = 0; c4 < 16; ++c4) {
      float4 v = xi[c4];
      acc += v.x * W_self[(4 * c4 + 0) * DOUT + lane];
      acc += v.y * W_self[(4 * c4 + 1) * DOUT + lane];
      acc += v.z * W_self[(4 * c4 + 2) * DOUT + lane];
      acc += v.w * W_self[(4 * c4 + 3) * DOUT + lane];
    }
    acc += pix * W_self[64 * DOUT + lane];
    acc += piy * W_self[65 * DOUT + lane];
    acc += piz * W_self[66 * DOUT + lane];
    acc += ri  * W_self[67 * DOUT + lane];
    acc = fmaxf(acc, 0.f);
    out[((size_t)b * TAU + (i - T0C)) * DOUT + lane] = acc;
  }
}

extern "C" void kernel_launch(void* const* d_in, const int* in_sizes, int n_in,
                              void* d_out, int out_size, void* d_ws, size_t ws_size,
                              hipStream_t stream) {
  (void)in_sizes; (void)n_in; (void)d_ws; (void)ws_size; (void)out_size;
  const float* x       = (const float*)d_in[0];
  const float* pos     = (const float*)d_in[1];
  const float* rot     = (const float*)d_in[2];
  const float* old_x   = (const float*)d_in[3];
  const float* old_pos = (const float*)d_in[4];
  const float* old_rot = (const float*)d_in[5];
  const float* W_self  = (const float*)d_in[6];
  const float* W_nbr   = (const float*)d_in[7];
  const float* bias    = (const float*)d_in[8];
  float* out = (float*)d_out;

  dim3 grid(NB + NCOPY), block(256);
  hipLaunchKernelGGL(navgcm, grid, block, 0, stream,
                     x, pos, rot, old_x, old_pos, old_rot, W_self, W_nbr, bias, out);
}

// Round 2
// 245.371 us; speedup vs baseline: 1.6819x; 1.6819x over previous
//
#include <hip/hip_runtime.h>
#include <cstdint>
#include <cstddef>

#define NB 2048
#define TAU 32
#define T0C 96
#define LQ 128      // T0 + tau
#define DD 64
#define DOUT 64
#define KK 16
#define SELB 256    // selection blocks (8 batches each)
#define NCOPY 1024

typedef unsigned long long u64;

// exact-rounding helpers: prevent fp-contract from fusing mul+add into fma,
// so d2 matches the reference's mul,mul,mul,add,add sequence bit-for-bit.
__device__ __forceinline__ float fmul_exact(float a, float b) {
  float r; asm("v_mul_f32 %0, %1, %2" : "=v"(r) : "v"(a), "v"(b)); return r;
}
__device__ __forceinline__ float fadd_exact(float a, float b) {
  float r; asm("v_add_f32 %0, %1, %2" : "=v"(r) : "v"(a), "v"(b)); return r;
}

// branchless insert of key into ascending sorted ks[0..15] (keep 16 smallest)
__device__ __forceinline__ void insert16(u64* ks, u64 key) {
  #pragma unroll
  for (int t = 15; t >= 1; --t) {
    u64 ins = (key < ks[t-1]) ? ks[t-1] : key;   // max(key, ks[t-1])
    ks[t] = (key < ks[t]) ? ins : ks[t];
  }
  ks[0] = (key < ks[0]) ? key : ks[0];
}

// ------------- Kernel 1: per-thread top-16 selection + output copies -------------
__global__ __launch_bounds__(256) void navgcm_sel(
    const float* __restrict__ x, const float* __restrict__ pos_in, const float* __restrict__ rot_in,
    const float* __restrict__ old_x, const float* __restrict__ old_pos, const float* __restrict__ old_rot,
    float* out)
{
  const int tid = threadIdx.x;

  if ((int)blockIdx.x >= SELB) {
    // ---------------- copy blocks ----------------
    const int g = (blockIdx.x - SELB) * 256 + tid;
    const int nthr = NCOPY * 256;

    // new_x as float4
    float4* dnx = (float4*)(out + (size_t)NB * TAU * DOUT);
    const float4* __restrict__ sox = (const float4*)old_x;
    const float4* __restrict__ sx  = (const float4*)x;
    const int NX4 = NB * LQ * DD / 4;  // 4,194,304
    for (int n = g; n < NX4; n += nthr) {
      int b = n >> 11;
      int r = n & 2047;
      int t = r >> 4;
      float4 v = (t < T0C) ? sox[(size_t)b * 2048 + r]
                           : sx[(size_t)b * 512 + (r - T0C * 16)];
      dnx[(size_t)b * 2048 + r] = v;
    }

    // new_pos + new_rot
    float* dpos = out + (size_t)NB * TAU * DOUT + (size_t)NB * LQ * DD;
    float* drot = dpos + (size_t)NB * LQ * 3;
    const int NROWS = NB * LQ;
    for (int n = g; n < NROWS; n += nthr) {
      int b = n >> 7, t = n & 127;
      float p0, p1, p2, rr;
      if (t < T0C) {
        const float* s = old_pos + (size_t)n * 3;
        p0 = s[0]; p1 = s[1]; p2 = s[2];
        rr = old_rot[n];
      } else {
        const float* s = pos_in + ((size_t)b * TAU + (t - T0C)) * 3;
        p0 = s[0]; p1 = s[1]; p2 = s[2];
        rr = rot_in[(size_t)b * TAU + (t - T0C)];
      }
      dpos[(size_t)n * 3 + 0] = p0;
      dpos[(size_t)n * 3 + 1] = p1;
      dpos[(size_t)n * 3 + 2] = p2;
      drot[n] = rr;
    }
    return;
  }

  // ---------------- selection blocks: 8 batches, 256 queries, 1/thread ----------------
  __shared__ float4 posb[LQ * 8];  // posb[j*8 + lb] = {px,py,pz,rot}

  #pragma unroll
  for (int r = 0; r < 4; ++r) {
    int n = tid + 256 * r;
    int lb = n & 7, j = n >> 3;
    int b = blockIdx.x * 8 + lb;
    float4 v;
    if (j < T0C) {
      const float* s = old_pos + ((size_t)b * LQ + j) * 3;
      v.x = s[0]; v.y = s[1]; v.z = s[2];
      v.w = old_rot[(size_t)b * LQ + j];
    } else {
      const float* s = pos_in + ((size_t)b * TAU + (j - T0C)) * 3;
      v.x = s[0]; v.y = s[1]; v.z = s[2];
      v.w = rot_in[(size_t)b * TAU + (j - T0C)];
    }
    posb[j * 8 + lb] = v;
  }
  __syncthreads();

  const int lb = tid >> 5;
  const int q  = tid & 31;
  const int i  = T0C + q;
  const int b  = blockIdx.x * 8 + lb;
  const float4 me = posb[i * 8 + lb];

  u64 ks[KK];
  #pragma unroll
  for (int t = 0; t < KK; ++t) ks[t] = ~0ULL;

  // j < 96: always causal
  #pragma unroll 2
  for (int j = 0; j < T0C; ++j) {
    float4 pj = posb[j * 8 + lb];
    float dx = me.x - pj.x, dy = me.y - pj.y, dz = me.z - pj.z;
    float d2 = fadd_exact(fadd_exact(fmul_exact(dx, dx), fmul_exact(dy, dy)),
                          fmul_exact(dz, dz));
    u64 key = (d2 <= 1.0f)
        ? ((((u64)__float_as_uint(d2)) << 32) | (unsigned)j) : ~0ULL;
    insert16(ks, key);
  }
  // j in [96, 127): causal check vs this thread's i
  #pragma unroll 2
  for (int j = T0C; j < LQ - 1; ++j) {
    float4 pj = posb[j * 8 + lb];
    float dx = me.x - pj.x, dy = me.y - pj.y, dz = me.z - pj.z;
    float d2 = fadd_exact(fadd_exact(fmul_exact(dx, dx), fmul_exact(dy, dy)),
                          fmul_exact(dz, dz));
    bool valid = (d2 <= 1.0f) && (j < i);
    u64 key = valid
        ? ((((u64)__float_as_uint(d2)) << 32) | (unsigned)j) : ~0ULL;
    insert16(ks, key);
  }

  // emit 16 u8 indices (127 = "zero row" sentinel) into this query's own out row
  uint32_t w[4] = {0u, 0u, 0u, 0u};
  #pragma unroll
  for (int t = 0; t < KK; ++t) {
    uint32_t hi = (uint32_t)(ks[t] >> 32);
    uint32_t jj = (hi == 0xffffffffu) ? 127u : (uint32_t)(ks[t] & 0x7fu);
    w[t >> 2] |= jj << ((t & 3) * 8);
  }
  uint4 st; st.x = w[0]; st.y = w[1]; st.z = w[2]; st.w = w[3];
  *reinterpret_cast<uint4*>(out + ((size_t)b * TAU + q) * DOUT) = st;
}

// ------------- Kernel 2: msg GEMM + gather + epilogue -------------
__global__ __launch_bounds__(256) void navgcm_main(
    const float* __restrict__ x, const float* __restrict__ pos_in, const float* __restrict__ rot_in,
    const float* __restrict__ old_x, const float* __restrict__ old_pos, const float* __restrict__ old_rot,
    const float* __restrict__ W_self, const float* __restrict__ W_nbr, const float* __restrict__ bias,
    float* out)
{
  const int b = blockIdx.x;
  const int tid = threadIdx.x;
  const int lane = tid & 63;
  const int wv = tid >> 6;

  __shared__ float px[LQ], py[LQ], pz[LQ], rt[LQ];
  __shared__ float msg[LQ * DOUT];  // 32 KB

  if (tid < LQ) {
    int t = tid;
    float p0, p1, p2, rr;
    if (t < T0C) {
      const float* s = old_pos + ((size_t)b * LQ + t) * 3;
      p0 = s[0]; p1 = s[1]; p2 = s[2];
      rr = old_rot[(size_t)b * LQ + t];
    } else {
      const float* s = pos_in + ((size_t)b * TAU + (t - T0C)) * 3;
      p0 = s[0]; p1 = s[1]; p2 = s[2];
      rr = rot_in[(size_t)b * TAU + (t - T0C)];
    }
    px[t] = p0; py[t] = p1; pz[t] = p2; rt[t] = rr;
  }

  // W_nbr column for this thread's output dim (o = lane)
  float wcol[68];
  #pragma unroll
  for (int c = 0; c < 68; ++c) wcol[c] = W_nbr[c * DOUT + lane];

  __syncthreads();

  // msg[j][o] = h[j] . W_nbr[:,o]; row 127 forced to 0 (sentinel sink)
  #pragma unroll 2
  for (int k = 0; k < 32; ++k) {
    int j = wv + 4 * k;
    const float4* hr = (j < T0C)
        ? (const float4*)(old_x + ((size_t)b * LQ + j) * DD)
        : (const float4*)(x + ((size_t)b * TAU + (j - T0C)) * DD);
    float acc = 0.f;
    #pragma unroll
    for (int c4 = 0; c4 < 16; ++c4) {
      float4 v = hr[c4];
      acc += v.x * wcol[4 * c4 + 0];
      acc += v.y * wcol[4 * c4 + 1];
      acc += v.z * wcol[4 * c4 + 2];
      acc += v.w * wcol[4 * c4 + 3];
    }
    acc += px[j] * wcol[64] + py[j] * wcol[65] + pz[j] * wcol[66] + rt[j] * wcol[67];
    msg[j * DOUT + lane] = (j == LQ - 1) ? 0.f : acc;
  }
  __syncthreads();

  // each wave handles 8 queries
  for (int q = 0; q < 8; ++q) {
    const int i = T0C + wv * 8 + q;
    float* rowp = out + ((size_t)b * TAU + (i - T0C)) * DOUT;

    // read the 16 neighbor indices K1 stashed in this row's first 16 bytes
    uint4 iv = *reinterpret_cast<const uint4*>(rowp);

    float agg = 0.f;
    #pragma unroll
    for (int s = 0; s < KK; ++s) {
      uint32_t word = (s < 4) ? iv.x : (s < 8) ? iv.y : (s < 12) ? iv.z : iv.w;
      int j = (word >> ((s & 3) * 8)) & 0xff;
      agg += msg[j * DOUT + lane];
    }

    // epilogue: out = relu(h[i] . W_self[:,o] + agg + bias[o])
    const float pix = px[i], piy = py[i], piz = pz[i], ri = rt[i];
    const float4* xi = (const float4*)(x + ((size_t)b * TAU + (i - T0C)) * DD);
    float acc = bias[lane] + agg;
    #pragma unroll
    for (int c4 = 0; c4 < 16; ++c4) {
      float4 v = xi[c4];
      acc += v.x * W_self[(4 * c4 + 0) * DOUT + lane];
      acc += v.y * W_self[(4 * c4 + 1) * DOUT + lane];
      acc += v.z * W_self[(4 * c4 + 2) * DOUT + lane];
      acc += v.w * W_self[(4 * c4 + 3) * DOUT + lane];
    }
    acc += pix * W_self[64 * DOUT + lane];
    acc += piy * W_self[65 * DOUT + lane];
    acc += piz * W_self[66 * DOUT + lane];
    acc += ri  * W_self[67 * DOUT + lane];
    acc = fmaxf(acc, 0.f);
    rowp[lane] = acc;
  }
}

extern "C" void kernel_launch(void* const* d_in, const int* in_sizes, int n_in,
                              void* d_out, int out_size, void* d_ws, size_t ws_size,
                              hipStream_t stream) {
  (void)in_sizes; (void)n_in; (void)d_ws; (void)ws_size; (void)out_size;
  const float* x       = (const float*)d_in[0];
  const float* pos     = (const float*)d_in[1];
  const float* rot     = (const float*)d_in[2];
  const float* old_x   = (const float*)d_in[3];
  const float* old_pos = (const float*)d_in[4];
  const float* old_rot = (const float*)d_in[5];
  const float* W_self  = (const float*)d_in[6];
  const float* W_nbr   = (const float*)d_in[7];
  const float* bias    = (const float*)d_in[8];
  float* out = (float*)d_out;

  hipLaunchKernelGGL(navgcm_sel, dim3(SELB + NCOPY), dim3(256), 0, stream,
                     x, pos, rot, old_x, old_pos, old_rot, out);
  hipLaunchKernelGGL(navgcm_main, dim3(NB), dim3(256), 0, stream,
                     x, pos, rot, old_x, old_pos, old_rot, W_self, W_nbr, bias, out);
}

// Round 3
// 72.012 us; speedup vs baseline: 5.7308x; 3.4073x over previous
//
#include <hip/hip_runtime.h>
#include <hip/hip_bf16.h>
#include <cstdint>
#include <cstddef>

#define NB 2048
#define TAU 32
#define T0C 96
#define LQ 128      // T0 + tau
#define DD 64
#define DOUT 64
#define KK 16
#define SELB 256    // selection blocks (8 batches each)
#define NCOPY 1024

typedef unsigned long long u64;
typedef __attribute__((ext_vector_type(8))) short short8;
typedef __attribute__((ext_vector_type(4))) float f32x4;

// exact-rounding helpers: keep d2 bit-identical to the reference (no fma fusion)
__device__ __forceinline__ float fmul_exact(float a, float b) {
  float r; asm("v_mul_f32 %0, %1, %2" : "=v"(r) : "v"(a), "v"(b)); return r;
}
__device__ __forceinline__ float fadd_exact(float a, float b) {
  float r; asm("v_add_f32 %0, %1, %2" : "=v"(r) : "v"(a), "v"(b)); return r;
}

__device__ __forceinline__ unsigned short f2bf(float f) {
  __hip_bfloat16 h = __float2bfloat16(f);
  return *reinterpret_cast<unsigned short*>(&h);
}

// branchless insert of key into ascending sorted ks[0..15] (keep 16 smallest)
__device__ __forceinline__ void insert16(u64* ks, u64 key) {
  #pragma unroll
  for (int t = 15; t >= 1; --t) {
    u64 ins = (key < ks[t-1]) ? ks[t-1] : key;
    ks[t] = (key < ks[t]) ? ins : ks[t];
  }
  ks[0] = (key < ks[0]) ? key : ks[0];
}

// ------------- Kernel 1: per-thread top-16 selection + output copies (unchanged) -------------
__global__ __launch_bounds__(256) void navgcm_sel(
    const float* __restrict__ x, const float* __restrict__ pos_in, const float* __restrict__ rot_in,
    const float* __restrict__ old_x, const float* __restrict__ old_pos, const float* __restrict__ old_rot,
    float* out)
{
  const int tid = threadIdx.x;

  if ((int)blockIdx.x >= SELB) {
    const int g = (blockIdx.x - SELB) * 256 + tid;
    const int nthr = NCOPY * 256;

    float4* dnx = (float4*)(out + (size_t)NB * TAU * DOUT);
    const float4* __restrict__ sox = (const float4*)old_x;
    const float4* __restrict__ sx  = (const float4*)x;
    const int NX4 = NB * LQ * DD / 4;
    for (int n = g; n < NX4; n += nthr) {
      int b = n >> 11;
      int r = n & 2047;
      int t = r >> 4;
      float4 v = (t < T0C) ? sox[(size_t)b * 2048 + r]
                           : sx[(size_t)b * 512 + (r - T0C * 16)];
      dnx[(size_t)b * 2048 + r] = v;
    }

    float* dpos = out + (size_t)NB * TAU * DOUT + (size_t)NB * LQ * DD;
    float* drot = dpos + (size_t)NB * LQ * 3;
    const int NROWS = NB * LQ;
    for (int n = g; n < NROWS; n += nthr) {
      int b = n >> 7, t = n & 127;
      float p0, p1, p2, rr;
      if (t < T0C) {
        const float* s = old_pos + (size_t)n * 3;
        p0 = s[0]; p1 = s[1]; p2 = s[2];
        rr = old_rot[n];
      } else {
        const float* s = pos_in + ((size_t)b * TAU + (t - T0C)) * 3;
        p0 = s[0]; p1 = s[1]; p2 = s[2];
        rr = rot_in[(size_t)b * TAU + (t - T0C)];
      }
      dpos[(size_t)n * 3 + 0] = p0;
      dpos[(size_t)n * 3 + 1] = p1;
      dpos[(size_t)n * 3 + 2] = p2;
      drot[n] = rr;
    }
    return;
  }

  __shared__ float4 posb[LQ * 8];

  #pragma unroll
  for (int r = 0; r < 4; ++r) {
    int n = tid + 256 * r;
    int lb = n & 7, j = n >> 3;
    int b = blockIdx.x * 8 + lb;
    float4 v;
    if (j < T0C) {
      const float* s = old_pos + ((size_t)b * LQ + j) * 3;
      v.x = s[0]; v.y = s[1]; v.z = s[2];
      v.w = old_rot[(size_t)b * LQ + j];
    } else {
      const float* s = pos_in + ((size_t)b * TAU + (j - T0C)) * 3;
      v.x = s[0]; v.y = s[1]; v.z = s[2];
      v.w = rot_in[(size_t)b * TAU + (j - T0C)];
    }
    posb[j * 8 + lb] = v;
  }
  __syncthreads();

  const int lb = tid >> 5;
  const int q  = tid & 31;
  const int i  = T0C + q;
  const int b  = blockIdx.x * 8 + lb;
  const float4 me = posb[i * 8 + lb];

  u64 ks[KK];
  #pragma unroll
  for (int t = 0; t < KK; ++t) ks[t] = ~0ULL;

  #pragma unroll 2
  for (int j = 0; j < T0C; ++j) {
    float4 pj = posb[j * 8 + lb];
    float dx = me.x - pj.x, dy = me.y - pj.y, dz = me.z - pj.z;
    float d2 = fadd_exact(fadd_exact(fmul_exact(dx, dx), fmul_exact(dy, dy)),
                          fmul_exact(dz, dz));
    u64 key = (d2 <= 1.0f)
        ? ((((u64)__float_as_uint(d2)) << 32) | (unsigned)j) : ~0ULL;
    insert16(ks, key);
  }
  #pragma unroll 2
  for (int j = T0C; j < LQ - 1; ++j) {
    float4 pj = posb[j * 8 + lb];
    float dx = me.x - pj.x, dy = me.y - pj.y, dz = me.z - pj.z;
    float d2 = fadd_exact(fadd_exact(fmul_exact(dx, dx), fmul_exact(dy, dy)),
                          fmul_exact(dz, dz));
    bool valid = (d2 <= 1.0f) && (j < i);
    u64 key = valid
        ? ((((u64)__float_as_uint(d2)) << 32) | (unsigned)j) : ~0ULL;
    insert16(ks, key);
  }

  uint32_t w[4] = {0u, 0u, 0u, 0u};
  #pragma unroll
  for (int t = 0; t < KK; ++t) {
    uint32_t hi = (uint32_t)(ks[t] >> 32);
    uint32_t jj = (hi == 0xffffffffu) ? 127u : (uint32_t)(ks[t] & 0x7fu);
    w[t >> 2] |= jj << ((t & 3) * 8);
  }
  uint4 st; st.x = w[0]; st.y = w[1]; st.z = w[2]; st.w = w[3];
  *reinterpret_cast<uint4*>(out + ((size_t)b * TAU + q) * DOUT) = st;
}

// ------------- Kernel 2: MFMA msg GEMM + gather + epilogue -------------
__global__ __launch_bounds__(256) void navgcm_mfma(
    const float* __restrict__ x, const float* __restrict__ pos_in, const float* __restrict__ rot_in,
    const float* __restrict__ old_x, const float* __restrict__ old_pos, const float* __restrict__ old_rot,
    const float* __restrict__ W_self, const float* __restrict__ W_nbr, const float* __restrict__ bias,
    float* out)
{
  const int b = blockIdx.x;
  const int tid = threadIdx.x;
  const int lane = tid & 63;
  const int wv = tid >> 6;
  const int fr = lane & 15;   // MFMA fragment row/col within tile
  const int fg = lane >> 4;   // MFMA fragment k-group / row-group

  __shared__ __align__(16) unsigned short Hs[LQ][72];    // bf16 bits, x-part of h
  __shared__ __align__(16) unsigned short Wn[DOUT][72];  // Wn[n][k] = bf16(W_nbr[k][n]), k<64
  __shared__ __align__(16) unsigned short Wsf[DOUT][72]; // same for W_self
  __shared__ float msgs[LQ][66];                         // f32 msg, stride-pad 66
  __shared__ float px[LQ], py[LQ], pz[LQ], rt[LQ];

  // ---- stage Hs: (row, 4-col group) per element-task ----
  #pragma unroll
  for (int it = 0; it < 8; ++it) {
    int n = tid + 256 * it;              // [0, 2048)
    int row = n >> 4, c4 = n & 15;
    const float4* src = (row < T0C)
        ? (const float4*)(old_x + ((size_t)b * LQ + row) * DD)
        : (const float4*)(x + ((size_t)b * TAU + (row - T0C)) * DD);
    float4 v = src[c4];
    ushort4 w4;
    w4.x = f2bf(v.x); w4.y = f2bf(v.y); w4.z = f2bf(v.z); w4.w = f2bf(v.w);
    *reinterpret_cast<ushort4*>(&Hs[row][c4 * 4]) = w4;
  }

  // ---- stage Wn / Wsf transposed ([n][k], k-contiguous), packed u32 writes ----
  #pragma unroll
  for (int it = 0; it < 8; ++it) {
    int m = tid + 256 * it;              // [0, 2048): n = m&63, kp = m>>6 in [0,32)
    int n = m & 63, kp = m >> 6;
    float a0 = W_nbr[(2 * kp) * DOUT + n], a1 = W_nbr[(2 * kp + 1) * DOUT + n];
    *reinterpret_cast<uint32_t*>(&Wn[n][2 * kp]) =
        (uint32_t)f2bf(a0) | ((uint32_t)f2bf(a1) << 16);
    float s0 = W_self[(2 * kp) * DOUT + n], s1 = W_self[(2 * kp + 1) * DOUT + n];
    *reinterpret_cast<uint32_t*>(&Wsf[n][2 * kp]) =
        (uint32_t)f2bf(s0) | ((uint32_t)f2bf(s1) << 16);
  }

  // ---- stage pos/rot (f32 exact) ----
  if (tid < LQ) {
    int t = tid;
    float p0, p1, p2, rr;
    if (t < T0C) {
      const float* s = old_pos + ((size_t)b * LQ + t) * 3;
      p0 = s[0]; p1 = s[1]; p2 = s[2];
      rr = old_rot[(size_t)b * LQ + t];
    } else {
      const float* s = pos_in + ((size_t)b * TAU + (t - T0C)) * 3;
      p0 = s[0]; p1 = s[1]; p2 = s[2];
      rr = rot_in[(size_t)b * TAU + (t - T0C)];
    }
    px[t] = p0; py[t] = p1; pz[t] = p2; rt[t] = rr;
  }
  __syncthreads();

  // ================= phase 1: msg = H[128][64] @ Wn^T + pos-terms =================
  // wave wv owns M-tiles {2wv, 2wv+1}; all 4 N-tiles; 2 K-steps.
  short8 bW[4][2];
  #pragma unroll
  for (int nt = 0; nt < 4; ++nt)
    #pragma unroll
    for (int ks = 0; ks < 2; ++ks)
      bW[nt][ks] = *reinterpret_cast<const short8*>(&Wn[nt * 16 + fr][ks * 32 + fg * 8]);

  f32x4 acc[2][4];
  #pragma unroll
  for (int m = 0; m < 2; ++m)
    #pragma unroll
    for (int n = 0; n < 4; ++n)
      acc[m][n] = (f32x4){0.f, 0.f, 0.f, 0.f};

  #pragma unroll
  for (int mtl = 0; mtl < 2; ++mtl) {
    int mrow = (2 * wv + mtl) * 16;
    short8 a0 = *reinterpret_cast<const short8*>(&Hs[mrow + fr][fg * 8]);
    short8 a1 = *reinterpret_cast<const short8*>(&Hs[mrow + fr][32 + fg * 8]);
    #pragma unroll
    for (int nt = 0; nt < 4; ++nt) {
      acc[mtl][nt] = __builtin_amdgcn_mfma_f32_16x16x32_bf16(a0, bW[nt][0], acc[mtl][nt], 0, 0, 0);
      acc[mtl][nt] = __builtin_amdgcn_mfma_f32_16x16x32_bf16(a1, bW[nt][1], acc[mtl][nt], 0, 0, 0);
    }
  }

  // pos/rot contribution (f32 VALU on the accumulator) + store msgs
  float wn4[4][4];
  #pragma unroll
  for (int nt = 0; nt < 4; ++nt) {
    int col = nt * 16 + fr;
    wn4[nt][0] = W_nbr[64 * DOUT + col];
    wn4[nt][1] = W_nbr[65 * DOUT + col];
    wn4[nt][2] = W_nbr[66 * DOUT + col];
    wn4[nt][3] = W_nbr[67 * DOUT + col];
  }
  #pragma unroll
  for (int mtl = 0; mtl < 2; ++mtl) {
    #pragma unroll
    for (int r = 0; r < 4; ++r) {
      int row = (2 * wv + mtl) * 16 + fg * 4 + r;   // C/D layout: row=(lane>>4)*4+reg
      float p0 = px[row], p1 = py[row], p2 = pz[row], p3 = rt[row];
      #pragma unroll
      for (int nt = 0; nt < 4; ++nt) {
        float v = acc[mtl][nt][r]
                + p0 * wn4[nt][0] + p1 * wn4[nt][1] + p2 * wn4[nt][2] + p3 * wn4[nt][3];
        // row 127 is never a valid neighbor (j < i <= 127); zero it so the
        // K1 sentinel index 127 contributes nothing to agg.
        msgs[row][nt * 16 + fr] = (row == LQ - 1) ? 0.f : v;
      }
    }
  }
  __syncthreads();

  // ================= phase 2: out rows 96..127 =================
  // wave wv: M-tile mt = wv&1 (query rows), N-tiles {2*(wv>>1), +1}
  const int mt = wv & 1;
  const int ntb = (wv >> 1) * 2;

  // preload neighbor-index stash (written by K1 into out) BEFORE anyone stores out
  uint4 stash[4];
  #pragma unroll
  for (int r = 0; r < 4; ++r) {
    int q = mt * 16 + fg * 4 + r;
    stash[r] = *reinterpret_cast<const uint4*>(out + ((size_t)b * TAU + q) * DOUT);
  }
  __syncthreads();

  short8 aQ0 = *reinterpret_cast<const short8*>(&Hs[T0C + mt * 16 + fr][fg * 8]);
  short8 aQ1 = *reinterpret_cast<const short8*>(&Hs[T0C + mt * 16 + fr][32 + fg * 8]);

  f32x4 acc2[2];
  #pragma unroll
  for (int n = 0; n < 2; ++n) acc2[n] = (f32x4){0.f, 0.f, 0.f, 0.f};
  #pragma unroll
  for (int ntl = 0; ntl < 2; ++ntl) {
    int nt = ntb + ntl;
    short8 b0 = *reinterpret_cast<const short8*>(&Wsf[nt * 16 + fr][fg * 8]);
    short8 b1 = *reinterpret_cast<const short8*>(&Wsf[nt * 16 + fr][32 + fg * 8]);
    acc2[ntl] = __builtin_amdgcn_mfma_f32_16x16x32_bf16(aQ0, b0, acc2[ntl], 0, 0, 0);
    acc2[ntl] = __builtin_amdgcn_mfma_f32_16x16x32_bf16(aQ1, b1, acc2[ntl], 0, 0, 0);
  }

  #pragma unroll
  for (int ntl = 0; ntl < 2; ++ntl) {
    int col = (ntb + ntl) * 16 + fr;
    float ws0 = W_self[64 * DOUT + col], ws1 = W_self[65 * DOUT + col];
    float ws2 = W_self[66 * DOUT + col], ws3 = W_self[67 * DOUT + col];
    float bi = bias[col];
    #pragma unroll
    for (int r = 0; r < 4; ++r) {
      int q = mt * 16 + fg * 4 + r;
      int row = T0C + q;
      float agg = 0.f;
      #pragma unroll
      for (int s = 0; s < KK; ++s) {
        uint32_t wd = (s < 4) ? stash[r].x : (s < 8) ? stash[r].y
                    : (s < 12) ? stash[r].z : stash[r].w;
        int j = (wd >> ((s & 3) * 8)) & 0xff;
        agg += msgs[j][col];
      }
      float v = acc2[ntl][r] + agg + bi
              + px[row] * ws0 + py[row] * ws1 + pz[row] * ws2 + rt[row] * ws3;
      v = fmaxf(v, 0.f);
      out[((size_t)b * TAU + q) * DOUT + col] = v;
    }
  }
}

extern "C" void kernel_launch(void* const* d_in, const int* in_sizes, int n_in,
                              void* d_out, int out_size, void* d_ws, size_t ws_size,
                              hipStream_t stream) {
  (void)in_sizes; (void)n_in; (void)d_ws; (void)ws_size; (void)out_size;
  const float* x       = (const float*)d_in[0];
  const float* pos     = (const float*)d_in[1];
  const float* rot     = (const float*)d_in[2];
  const float* old_x   = (const float*)d_in[3];
  const float* old_pos = (const float*)d_in[4];
  const float* old_rot = (const float*)d_in[5];
  const float* W_self  = (const float*)d_in[6];
  const float* W_nbr   = (const float*)d_in[7];
  const float* bias    = (const float*)d_in[8];
  float* out = (float*)d_out;

  hipLaunchKernelGGL(navgcm_sel, dim3(SELB + NCOPY), dim3(256), 0, stream,
                     x, pos, rot, old_x, old_pos, old_rot, out);
  hipLaunchKernelGGL(navgcm_mfma, dim3(NB), dim3(256), 0, stream,
                     x, pos, rot, old_x, old_pos, old_rot, W_self, W_nbr, bias, out);
}

// Round 4
// 65.256 us; speedup vs baseline: 6.3241x; 1.1035x over previous
//
#include <hip/hip_runtime.h>
#include <hip/hip_bf16.h>
#include <cstdint>
#include <cstddef>

#define NB 2048
#define TAU 32
#define T0C 96
#define LQ 128      // T0 + tau
#define DD 64
#define DOUT 64
#define KK 16

typedef unsigned long long u64;
typedef __attribute__((ext_vector_type(8))) short short8;
typedef __attribute__((ext_vector_type(4))) float f32x4;

// exact-rounding helpers: keep d2 bit-identical to the reference (no fma fusion)
__device__ __forceinline__ float fmul_exact(float a, float b) {
  float r; asm("v_mul_f32 %0, %1, %2" : "=v"(r) : "v"(a), "v"(b)); return r;
}
__device__ __forceinline__ float fadd_exact(float a, float b) {
  float r; asm("v_add_f32 %0, %1, %2" : "=v"(r) : "v"(a), "v"(b)); return r;
}
__device__ __forceinline__ unsigned short f2bf(float f) {
  __hip_bfloat16 h = __float2bfloat16(f);
  return *reinterpret_cast<unsigned short*>(&h);
}

__global__ __launch_bounds__(256) void navgcm_fused(
    const float* __restrict__ x, const float* __restrict__ pos_in, const float* __restrict__ rot_in,
    const float* __restrict__ old_x, const float* __restrict__ old_pos, const float* __restrict__ old_rot,
    const float* __restrict__ W_self, const float* __restrict__ W_nbr, const float* __restrict__ bias,
    float* __restrict__ outp)
{
  const int b = blockIdx.x;
  const int tid = threadIdx.x;
  const int lane = tid & 63;
  const int wv = tid >> 6;
  const int fr = lane & 15;   // MFMA fragment row/col within tile
  const int fg = lane >> 4;   // MFMA fragment k-group / row-group

  __shared__ __align__(16) unsigned short Hs[LQ][72];    // bf16 x-part of h
  __shared__ __align__(16) unsigned short Wn[DOUT][72];  // Wn[n][k] = bf16(W_nbr[k][n])
  __shared__ __align__(16) unsigned short Wsf[DOUT][72];
  // union region: selection keys u64[32][8][17] (34816 B)  <->  msgs f32[128][66] (33792 B)
  __shared__ __align__(16) unsigned char uni[34816];
  __shared__ float px[LQ], py[LQ], pz[LQ], rt[LQ];
  __shared__ uint4 selidx[32];

  float (*msgs)[66] = reinterpret_cast<float(*)[66]>(uni);
  u64 (*Kl)[8][17] = reinterpret_cast<u64(*)[8][17]>(uni);

  // ================= phase A: copy + stage =================
  // new_x copy + bf16 stage from one read of old_x/x
  float4* dnx = (float4*)(outp + (size_t)NB * TAU * DOUT);
  #pragma unroll
  for (int it = 0; it < 8; ++it) {
    int n = tid + 256 * it;              // [0,2048): row = n>>4, c4 = n&15
    int row = n >> 4, c4 = n & 15;
    const float4* src = (row < T0C)
        ? (const float4*)(old_x + ((size_t)b * LQ + row) * DD)
        : (const float4*)(x + ((size_t)b * TAU + (row - T0C)) * DD);
    float4 v = src[c4];
    dnx[(size_t)b * 2048 + n] = v;       // new_x
    ushort4 w4;
    w4.x = f2bf(v.x); w4.y = f2bf(v.y); w4.z = f2bf(v.z); w4.w = f2bf(v.w);
    *reinterpret_cast<ushort4*>(&Hs[row][c4 * 4]) = w4;
  }

  // weights transposed into LDS ([n][k], k-contiguous)
  #pragma unroll
  for (int it = 0; it < 8; ++it) {
    int m = tid + 256 * it;              // n = m&63, kp = m>>6 in [0,32)
    int n = m & 63, kp = m >> 6;
    float a0 = W_nbr[(2 * kp) * DOUT + n], a1 = W_nbr[(2 * kp + 1) * DOUT + n];
    *reinterpret_cast<uint32_t*>(&Wn[n][2 * kp]) =
        (uint32_t)f2bf(a0) | ((uint32_t)f2bf(a1) << 16);
    float s0 = W_self[(2 * kp) * DOUT + n], s1 = W_self[(2 * kp + 1) * DOUT + n];
    *reinterpret_cast<uint32_t*>(&Wsf[n][2 * kp]) =
        (uint32_t)f2bf(s0) | ((uint32_t)f2bf(s1) << 16);
  }

  // pos/rot: stage f32-exact + copy to new_pos/new_rot
  float* dpos = outp + (size_t)NB * TAU * DOUT + (size_t)NB * LQ * DD;
  float* drot = dpos + (size_t)NB * LQ * 3;
  if (tid < LQ) {
    int t = tid;
    float p0, p1, p2, rr;
    if (t < T0C) {
      const float* s = old_pos + ((size_t)b * LQ + t) * 3;
      p0 = s[0]; p1 = s[1]; p2 = s[2];
      rr = old_rot[(size_t)b * LQ + t];
    } else {
      const float* s = pos_in + ((size_t)b * TAU + (t - T0C)) * 3;
      p0 = s[0]; p1 = s[1]; p2 = s[2];
      rr = rot_in[(size_t)b * TAU + (t - T0C)];
    }
    px[t] = p0; py[t] = p1; pz[t] = p2; rt[t] = rr;
    size_t g = (size_t)b * LQ + t;
    dpos[g * 3 + 0] = p0; dpos[g * 3 + 1] = p1; dpos[g * 3 + 2] = p2;
    drot[g] = rr;
  }
  __syncthreads();   // b1: Hs/Wn/Wsf/pos ready

  // ================= phase B1: partial selection (8 threads/query) =================
  {
    const int q = tid >> 3, s8 = tid & 7;
    const int i = T0C + q;
    const int j0 = s8 * 16;
    const float pix = px[i], piy = py[i], piz = pz[i];
    u64 k0 = ~0ULL, k1 = ~0ULL, k2 = ~0ULL, k3 = ~0ULL, k4 = ~0ULL, k5 = ~0ULL,
        k6 = ~0ULL, k7 = ~0ULL, k8 = ~0ULL, k9 = ~0ULL, k10 = ~0ULL, k11 = ~0ULL,
        k12 = ~0ULL, k13 = ~0ULL, k14 = ~0ULL, k15 = ~0ULL;
#define INS_STEP(prev, cur) { u64 mx = (_k < prev) ? prev : _k; cur = (_k < cur) ? mx : cur; }
#define INSERT_K() do { \
    INS_STEP(k14, k15) INS_STEP(k13, k14) INS_STEP(k12, k13) INS_STEP(k11, k12) \
    INS_STEP(k10, k11) INS_STEP(k9, k10)  INS_STEP(k8, k9)   INS_STEP(k7, k8)  \
    INS_STEP(k6, k7)   INS_STEP(k5, k6)   INS_STEP(k4, k5)   INS_STEP(k3, k4)  \
    INS_STEP(k2, k3)   INS_STEP(k1, k2)   INS_STEP(k0, k1)   \
    k0 = (_k < k0) ? _k : k0; } while (0)
    #pragma unroll
    for (int c = 0; c < 16; ++c) {
      int j = j0 + c;
      float dx = pix - px[j], dy = piy - py[j], dz = piz - pz[j];
      float d2 = fadd_exact(fadd_exact(fmul_exact(dx, dx), fmul_exact(dy, dy)),
                            fmul_exact(dz, dz));
      u64 _k = ((d2 <= 1.0f) && (j < i))
          ? ((((u64)__float_as_uint(d2)) << 32) | (unsigned)j) : ~0ULL;
      INSERT_K();
    }
    u64* dst = &Kl[q][s8][0];
    dst[0] = k0;  dst[1] = k1;  dst[2] = k2;  dst[3] = k3;
    dst[4] = k4;  dst[5] = k5;  dst[6] = k6;  dst[7] = k7;
    dst[8] = k8;  dst[9] = k9;  dst[10] = k10; dst[11] = k11;
    dst[12] = k12; dst[13] = k13; dst[14] = k14; dst[15] = k15;
  }

  // ================= phase B2: msg MFMA into registers (no LDS writes yet) =================
  short8 bW[4][2];
  #pragma unroll
  for (int nt = 0; nt < 4; ++nt)
    #pragma unroll
    for (int ks = 0; ks < 2; ++ks)
      bW[nt][ks] = *reinterpret_cast<const short8*>(&Wn[nt * 16 + fr][ks * 32 + fg * 8]);

  f32x4 acc[2][4];
  #pragma unroll
  for (int m = 0; m < 2; ++m)
    #pragma unroll
    for (int n = 0; n < 4; ++n)
      acc[m][n] = (f32x4){0.f, 0.f, 0.f, 0.f};

  #pragma unroll
  for (int mtl = 0; mtl < 2; ++mtl) {
    int mrow = (2 * wv + mtl) * 16;
    short8 a0 = *reinterpret_cast<const short8*>(&Hs[mrow + fr][fg * 8]);
    short8 a1 = *reinterpret_cast<const short8*>(&Hs[mrow + fr][32 + fg * 8]);
    #pragma unroll
    for (int nt = 0; nt < 4; ++nt) {
      acc[mtl][nt] = __builtin_amdgcn_mfma_f32_16x16x32_bf16(a0, bW[nt][0], acc[mtl][nt], 0, 0, 0);
      acc[mtl][nt] = __builtin_amdgcn_mfma_f32_16x16x32_bf16(a1, bW[nt][1], acc[mtl][nt], 0, 0, 0);
    }
  }
  __syncthreads();   // b2: all Kl sublists written

  // ================= phase B3: 8-way merge (1 thread/query) ∥ self-MFMA =================
  if (tid < 32) {
    const int q = tid;
    int h0 = 0, h1 = 0, h2 = 0, h3 = 0, h4 = 0, h5 = 0, h6 = 0, h7 = 0;
    uint32_t w0 = 0, w1 = 0, w2 = 0, w3 = 0;
    #pragma unroll
    for (int t = 0; t < KK; ++t) {
      u64 best = ~0ULL; int bs = -1;
#define MSTEP(S, HS) { u64 v = Kl[q][S][HS]; if (v < best) { best = v; bs = S; } }
      MSTEP(0, h0) MSTEP(1, h1) MSTEP(2, h2) MSTEP(3, h3)
      MSTEP(4, h4) MSTEP(5, h5) MSTEP(6, h6) MSTEP(7, h7)
#undef MSTEP
      uint32_t jj = (best == ~0ULL) ? 127u : (uint32_t)(best & 0x7fu);
      if (t < 4)       w0 |= jj << ((t & 3) * 8);
      else if (t < 8)  w1 |= jj << ((t & 3) * 8);
      else if (t < 12) w2 |= jj << ((t & 3) * 8);
      else             w3 |= jj << ((t & 3) * 8);
      h0 += (bs == 0); h1 += (bs == 1); h2 += (bs == 2); h3 += (bs == 3);
      h4 += (bs == 4); h5 += (bs == 5); h6 += (bs == 6); h7 += (bs == 7);
    }
    uint4 sv; sv.x = w0; sv.y = w1; sv.z = w2; sv.w = w3;
    selidx[tid] = sv;
  }

  // self-term MFMA (all threads, registers only)
  const int mt = wv & 1;
  const int ntb = (wv >> 1) * 2;
  short8 aQ0 = *reinterpret_cast<const short8*>(&Hs[T0C + mt * 16 + fr][fg * 8]);
  short8 aQ1 = *reinterpret_cast<const short8*>(&Hs[T0C + mt * 16 + fr][32 + fg * 8]);
  f32x4 acc2[2];
  #pragma unroll
  for (int n = 0; n < 2; ++n) acc2[n] = (f32x4){0.f, 0.f, 0.f, 0.f};
  #pragma unroll
  for (int ntl = 0; ntl < 2; ++ntl) {
    int nt = ntb + ntl;
    short8 b0 = *reinterpret_cast<const short8*>(&Wsf[nt * 16 + fr][fg * 8]);
    short8 b1 = *reinterpret_cast<const short8*>(&Wsf[nt * 16 + fr][32 + fg * 8]);
    acc2[ntl] = __builtin_amdgcn_mfma_f32_16x16x32_bf16(aQ0, b0, acc2[ntl], 0, 0, 0);
    acc2[ntl] = __builtin_amdgcn_mfma_f32_16x16x32_bf16(aQ1, b1, acc2[ntl], 0, 0, 0);
  }
  __syncthreads();   // b3: selidx ready, Kl dead -> uni reusable as msgs

  // ================= phase B4: msgs = acc + pos-terms -> LDS =================
  float wn4[4][4];
  #pragma unroll
  for (int nt = 0; nt < 4; ++nt) {
    int col = nt * 16 + fr;
    wn4[nt][0] = W_nbr[64 * DOUT + col];
    wn4[nt][1] = W_nbr[65 * DOUT + col];
    wn4[nt][2] = W_nbr[66 * DOUT + col];
    wn4[nt][3] = W_nbr[67 * DOUT + col];
  }
  #pragma unroll
  for (int mtl = 0; mtl < 2; ++mtl) {
    #pragma unroll
    for (int r = 0; r < 4; ++r) {
      int row = (2 * wv + mtl) * 16 + fg * 4 + r;   // C/D: row=(lane>>4)*4+reg
      float p0 = px[row], p1 = py[row], p2 = pz[row], p3 = rt[row];
      #pragma unroll
      for (int nt = 0; nt < 4; ++nt) {
        float v = acc[mtl][nt][r]
                + p0 * wn4[nt][0] + p1 * wn4[nt][1] + p2 * wn4[nt][2] + p3 * wn4[nt][3];
        msgs[row][nt * 16 + fr] = (row == LQ - 1) ? 0.f : v;  // row 127 = sentinel sink
      }
    }
  }
  __syncthreads();   // b4: msgs ready

  // ================= phase B5: gather + epilogue =================
  #pragma unroll
  for (int ntl = 0; ntl < 2; ++ntl) {
    int col = (ntb + ntl) * 16 + fr;
    float ws0 = W_self[64 * DOUT + col], ws1 = W_self[65 * DOUT + col];
    float ws2 = W_self[66 * DOUT + col], ws3 = W_self[67 * DOUT + col];
    float bi = bias[col];
    #pragma unroll
    for (int r = 0; r < 4; ++r) {
      int q = mt * 16 + fg * 4 + r;
      int row = T0C + q;
      uint4 sv = selidx[q];
      float agg = 0.f;
      #pragma unroll
      for (int s = 0; s < KK; ++s) {
        uint32_t wd = (s < 4) ? sv.x : (s < 8) ? sv.y : (s < 12) ? sv.z : sv.w;
        int j = (wd >> ((s & 3) * 8)) & 0xff;
        agg += msgs[j][col];
      }
      float v = acc2[ntl][r] + agg + bi
              + px[row] * ws0 + py[row] * ws1 + pz[row] * ws2 + rt[row] * ws3;
      v = fmaxf(v, 0.f);
      outp[((size_t)b * TAU + q) * DOUT + col] = v;
    }
  }
}

extern "C" void kernel_launch(void* const* d_in, const int* in_sizes, int n_in,
                              void* d_out, int out_size, void* d_ws, size_t ws_size,
                              hipStream_t stream) {
  (void)in_sizes; (void)n_in; (void)d_ws; (void)ws_size; (void)out_size;
  const float* x       = (const float*)d_in[0];
  const float* pos     = (const float*)d_in[1];
  const float* rot     = (const float*)d_in[2];
  const float* old_x   = (const float*)d_in[3];
  const float* old_pos = (const float*)d_in[4];
  const float* old_rot = (const float*)d_in[5];
  const float* W_self  = (const float*)d_in[6];
  const float* W_nbr   = (const float*)d_in[7];
  const float* bias    = (const float*)d_in[8];
  float* out = (float*)d_out;

  hipLaunchKernelGGL(navgcm_fused, dim3(NB), dim3(256), 0, stream,
                     x, pos, rot, old_x, old_pos, old_rot, W_self, W_nbr, bias, out);
}

// Round 5
// 50.220 us; speedup vs baseline: 8.2175x; 1.2994x over previous
//
#include <hip/hip_runtime.h>
#include <hip/hip_bf16.h>
#include <cstdint>
#include <cstddef>

#define NB 2048
#define TAU 32
#define T0C 96
#define LQ 128      // T0 + tau
#define DD 64
#define DOUT 64
#define KK 16

typedef unsigned long long u64;
typedef __attribute__((ext_vector_type(8))) short short8;
typedef __attribute__((ext_vector_type(4))) float f32x4;

#define KINV 1e30   // invalid-key sentinel (valid keys < 2^38)

// exact-rounding helpers: keep d2 bit-identical to the reference (no fma fusion)
__device__ __forceinline__ float fmul_exact(float a, float b) {
  float r; asm("v_mul_f32 %0, %1, %2" : "=v"(r) : "v"(a), "v"(b)); return r;
}
__device__ __forceinline__ float fadd_exact(float a, float b) {
  float r; asm("v_add_f32 %0, %1, %2" : "=v"(r) : "v"(a), "v"(b)); return r;
}
__device__ __forceinline__ unsigned short f2bf(float f) {
  __hip_bfloat16 h = __float2bfloat16(f);
  return *reinterpret_cast<unsigned short*>(&h);
}
__device__ __forceinline__ double shfl_xor_f64(double v, int mask) {
  u64 u = __double_as_longlong(v);
  int lo = __shfl_xor((int)(unsigned)(u & 0xffffffffULL), mask, 64);
  int hi = __shfl_xor((int)(unsigned)(u >> 32), mask, 64);
  return __longlong_as_double(((u64)(unsigned)hi << 32) | (unsigned)lo);
}

// compare-exchange: ascending (min to first) / descending (max to first)
#define CA(i, j) { double _lo = fmin(kd[i], kd[j]); double _hi = fmax(kd[i], kd[j]); kd[i] = _lo; kd[j] = _hi; }
#define CD(i, j) { double _lo = fmin(kd[i], kd[j]); double _hi = fmax(kd[i], kd[j]); kd[i] = _hi; kd[j] = _lo; }

// full bitonic sort of kd[0..15], ascending (static network, 80 CAS)
#define SORT16() do { \
  CA(0,1)  CD(2,3)  CA(4,5)  CD(6,7)  CA(8,9)  CD(10,11) CA(12,13) CD(14,15) \
  CA(0,2)  CA(1,3)  CD(4,6)  CD(5,7)  CA(8,10) CA(9,11)  CD(12,14) CD(13,15) \
  CA(0,1)  CA(2,3)  CD(4,5)  CD(6,7)  CA(8,9)  CA(10,11) CD(12,13) CD(14,15) \
  CA(0,4)  CA(1,5)  CA(2,6)  CA(3,7)  CD(8,12) CD(9,13)  CD(10,14) CD(11,15) \
  CA(0,2)  CA(1,3)  CA(4,6)  CA(5,7)  CD(8,10) CD(9,11)  CD(12,14) CD(13,15) \
  CA(0,1)  CA(2,3)  CA(4,5)  CA(6,7)  CD(8,9)  CD(10,11) CD(12,13) CD(14,15) \
  CA(0,8)  CA(1,9)  CA(2,10) CA(3,11) CA(4,12) CA(5,13)  CA(6,14)  CA(7,15)  \
  CA(0,4)  CA(1,5)  CA(2,6)  CA(3,7)  CA(8,12) CA(9,13)  CA(10,14) CA(11,15) \
  CA(0,2)  CA(1,3)  CA(4,6)  CA(5,7)  CA(8,10) CA(9,11)  CA(12,14) CA(13,15) \
  CA(0,1)  CA(2,3)  CA(4,5)  CA(6,7)  CA(8,9)  CA(10,11) CA(12,13) CA(14,15) \
} while (0)

// bitonic merge of a bitonic kd[0..15] -> ascending (4 stages, 32 CAS)
#define MERGE16() do { \
  CA(0,8)  CA(1,9)  CA(2,10) CA(3,11) CA(4,12) CA(5,13)  CA(6,14)  CA(7,15)  \
  CA(0,4)  CA(1,5)  CA(2,6)  CA(3,7)  CA(8,12) CA(9,13)  CA(10,14) CA(11,15) \
  CA(0,2)  CA(1,3)  CA(4,6)  CA(5,7)  CA(8,10) CA(9,11)  CA(12,14) CA(13,15) \
  CA(0,1)  CA(2,3)  CA(4,5)  CA(6,7)  CA(8,9)  CA(10,11) CA(12,13) CA(14,15) \
} while (0)

// merge sorted kd with partner lane's sorted list (xor mask), keep lowest 16
#define SHUF_MERGE(mask) do { \
  double pb[16]; \
  _Pragma("unroll") \
  for (int _i = 0; _i < 16; ++_i) pb[_i] = shfl_xor_f64(kd[15 - _i], mask); \
  _Pragma("unroll") \
  for (int _i = 0; _i < 16; ++_i) kd[_i] = fmin(kd[_i], pb[_i]); \
  MERGE16(); \
} while (0)

__global__ __launch_bounds__(256, 2) void navgcm_fused(
    const float* __restrict__ x, const float* __restrict__ pos_in, const float* __restrict__ rot_in,
    const float* __restrict__ old_x, const float* __restrict__ old_pos, const float* __restrict__ old_rot,
    const float* __restrict__ W_self, const float* __restrict__ W_nbr, const float* __restrict__ bias,
    float* __restrict__ outp)
{
  const int b = blockIdx.x;
  const int tid = threadIdx.x;
  const int lane = tid & 63;
  const int wv = tid >> 6;
  const int fr = lane & 15;   // MFMA fragment row/col within tile
  const int fg = lane >> 4;   // MFMA fragment k-group / row-group

  __shared__ __align__(16) unsigned short Hs[LQ][72];    // bf16 x-part of h
  __shared__ __align__(16) unsigned short Wn[DOUT][72];  // Wn[n][k] = bf16(W_nbr[k][n])
  __shared__ __align__(16) unsigned short Wsf[DOUT][72];
  __shared__ float msgs[LQ][66];
  __shared__ float px[LQ], py[LQ], pz[LQ], rt[LQ];
  __shared__ uint4 selidx[32];

  // ================= phase A: copy + stage =================
  float4* dnx = (float4*)(outp + (size_t)NB * TAU * DOUT);
  #pragma unroll
  for (int it = 0; it < 8; ++it) {
    int n = tid + 256 * it;              // [0,2048): row = n>>4, c4 = n&15
    int row = n >> 4, c4 = n & 15;
    const float4* src = (row < T0C)
        ? (const float4*)(old_x + ((size_t)b * LQ + row) * DD)
        : (const float4*)(x + ((size_t)b * TAU + (row - T0C)) * DD);
    float4 v = src[c4];
    dnx[(size_t)b * 2048 + n] = v;       // new_x
    ushort4 w4;
    w4.x = f2bf(v.x); w4.y = f2bf(v.y); w4.z = f2bf(v.z); w4.w = f2bf(v.w);
    *reinterpret_cast<ushort4*>(&Hs[row][c4 * 4]) = w4;
  }

  #pragma unroll
  for (int it = 0; it < 8; ++it) {
    int m = tid + 256 * it;              // n = m&63, kp = m>>6 in [0,32)
    int n = m & 63, kp = m >> 6;
    float a0 = W_nbr[(2 * kp) * DOUT + n], a1 = W_nbr[(2 * kp + 1) * DOUT + n];
    *reinterpret_cast<uint32_t*>(&Wn[n][2 * kp]) =
        (uint32_t)f2bf(a0) | ((uint32_t)f2bf(a1) << 16);
    float s0 = W_self[(2 * kp) * DOUT + n], s1 = W_self[(2 * kp + 1) * DOUT + n];
    *reinterpret_cast<uint32_t*>(&Wsf[n][2 * kp]) =
        (uint32_t)f2bf(s0) | ((uint32_t)f2bf(s1) << 16);
  }

  float* dpos = outp + (size_t)NB * TAU * DOUT + (size_t)NB * LQ * DD;
  float* drot = dpos + (size_t)NB * LQ * 3;
  if (tid < LQ) {
    int t = tid;
    float p0, p1, p2, rr;
    if (t < T0C) {
      const float* s = old_pos + ((size_t)b * LQ + t) * 3;
      p0 = s[0]; p1 = s[1]; p2 = s[2];
      rr = old_rot[(size_t)b * LQ + t];
    } else {
      const float* s = pos_in + ((size_t)b * TAU + (t - T0C)) * 3;
      p0 = s[0]; p1 = s[1]; p2 = s[2];
      rr = rot_in[(size_t)b * TAU + (t - T0C)];
    }
    px[t] = p0; py[t] = p1; pz[t] = p2; rt[t] = rr;
    size_t g = (size_t)b * LQ + t;
    dpos[g * 3 + 0] = p0; dpos[g * 3 + 1] = p1; dpos[g * 3 + 2] = p2;
    drot[g] = rr;
  }
  __syncthreads();   // b1: Hs/Wn/Wsf/pos ready

  // ========== phase B: selection, fully in registers + shuffles ==========
  // 8 threads/query; thread s8 scans j = 8c + s8 (interleaved -> broadcast
  // LDS reads). Key = d2bits*128 + j as f64 (exact; order == (d2,j) lex).
  {
    const int q = tid >> 3, s8 = tid & 7;
    const int i = T0C + q;
    const float pix = px[i], piy = py[i], piz = pz[i];
    double kd[16];
    #pragma unroll
    for (int c = 0; c < 16; ++c) {
      int j = 8 * c + s8;
      float dx = pix - px[j], dy = piy - py[j], dz = piz - pz[j];
      float d2 = fadd_exact(fadd_exact(fmul_exact(dx, dx), fmul_exact(dy, dy)),
                            fmul_exact(dz, dz));
      bool valid = (d2 <= 1.0f) && (j < i);
      double key = fma((double)__float_as_uint(d2), 128.0, (double)j);
      kd[c] = valid ? key : KINV;
    }
    SORT16();          // ascending per-thread sublist
    SHUF_MERGE(1);     // 8 -> 4 lists
    SHUF_MERGE(2);     // 4 -> 2
    SHUF_MERGE(4);     // 2 -> 1: all 8 lanes now hold the final sorted 16

    if (s8 == 0) {
      uint32_t w[4] = {0u, 0u, 0u, 0u};
      #pragma unroll
      for (int t = 0; t < KK; ++t) {
        double kv = kd[t];
        uint32_t jj;
        if (kv >= 1e29) {
          jj = 127u;                         // sentinel -> zero msg row
        } else {
          uint32_t d2b = (uint32_t)(kv * 0.0078125);       // trunc(kv/128)
          double rem = kv - 128.0 * (double)d2b;           // exact
          jj = (uint32_t)rem;
        }
        w[t >> 2] |= jj << ((t & 3) * 8);
      }
      uint4 sv; sv.x = w[0]; sv.y = w[1]; sv.z = w[2]; sv.w = w[3];
      selidx[q] = sv;
    }
  }

  // ================= phase C: msg MFMA (acc) =================
  short8 bW[4][2];
  #pragma unroll
  for (int nt = 0; nt < 4; ++nt)
    #pragma unroll
    for (int ks = 0; ks < 2; ++ks)
      bW[nt][ks] = *reinterpret_cast<const short8*>(&Wn[nt * 16 + fr][ks * 32 + fg * 8]);

  f32x4 acc[2][4];
  #pragma unroll
  for (int m = 0; m < 2; ++m)
    #pragma unroll
    for (int n = 0; n < 4; ++n)
      acc[m][n] = (f32x4){0.f, 0.f, 0.f, 0.f};

  #pragma unroll
  for (int mtl = 0; mtl < 2; ++mtl) {
    int mrow = (2 * wv + mtl) * 16;
    short8 a0 = *reinterpret_cast<const short8*>(&Hs[mrow + fr][fg * 8]);
    short8 a1 = *reinterpret_cast<const short8*>(&Hs[mrow + fr][32 + fg * 8]);
    #pragma unroll
    for (int nt = 0; nt < 4; ++nt) {
      acc[mtl][nt] = __builtin_amdgcn_mfma_f32_16x16x32_bf16(a0, bW[nt][0], acc[mtl][nt], 0, 0, 0);
      acc[mtl][nt] = __builtin_amdgcn_mfma_f32_16x16x32_bf16(a1, bW[nt][1], acc[mtl][nt], 0, 0, 0);
    }
  }

  // self-term MFMA (registers only)
  const int mt = wv & 1;
  const int ntb = (wv >> 1) * 2;
  short8 aQ0 = *reinterpret_cast<const short8*>(&Hs[T0C + mt * 16 + fr][fg * 8]);
  short8 aQ1 = *reinterpret_cast<const short8*>(&Hs[T0C + mt * 16 + fr][32 + fg * 8]);
  f32x4 acc2[2];
  #pragma unroll
  for (int n = 0; n < 2; ++n) acc2[n] = (f32x4){0.f, 0.f, 0.f, 0.f};
  #pragma unroll
  for (int ntl = 0; ntl < 2; ++ntl) {
    int nt = ntb + ntl;
    short8 b0 = *reinterpret_cast<const short8*>(&Wsf[nt * 16 + fr][fg * 8]);
    short8 b1 = *reinterpret_cast<const short8*>(&Wsf[nt * 16 + fr][32 + fg * 8]);
    acc2[ntl] = __builtin_amdgcn_mfma_f32_16x16x32_bf16(aQ0, b0, acc2[ntl], 0, 0, 0);
    acc2[ntl] = __builtin_amdgcn_mfma_f32_16x16x32_bf16(aQ1, b1, acc2[ntl], 0, 0, 0);
  }

  // ================= phase D: msgs = acc + pos-terms -> LDS =================
  float wn4[4][4];
  #pragma unroll
  for (int nt = 0; nt < 4; ++nt) {
    int col = nt * 16 + fr;
    wn4[nt][0] = W_nbr[64 * DOUT + col];
    wn4[nt][1] = W_nbr[65 * DOUT + col];
    wn4[nt][2] = W_nbr[66 * DOUT + col];
    wn4[nt][3] = W_nbr[67 * DOUT + col];
  }
  #pragma unroll
  for (int mtl = 0; mtl < 2; ++mtl) {
    #pragma unroll
    for (int r = 0; r < 4; ++r) {
      int row = (2 * wv + mtl) * 16 + fg * 4 + r;   // C/D: row=(lane>>4)*4+reg
      float p0 = px[row], p1 = py[row], p2 = pz[row], p3 = rt[row];
      #pragma unroll
      for (int nt = 0; nt < 4; ++nt) {
        float v = acc[mtl][nt][r]
                + p0 * wn4[nt][0] + p1 * wn4[nt][1] + p2 * wn4[nt][2] + p3 * wn4[nt][3];
        msgs[row][nt * 16 + fr] = (row == LQ - 1) ? 0.f : v;  // row 127 = sentinel sink
      }
    }
  }
  __syncthreads();   // b2: msgs + selidx ready

  // ================= phase E: gather + epilogue =================
  #pragma unroll
  for (int ntl = 0; ntl < 2; ++ntl) {
    int col = (ntb + ntl) * 16 + fr;
    float ws0 = W_self[64 * DOUT + col], ws1 = W_self[65 * DOUT + col];
    float ws2 = W_self[66 * DOUT + col], ws3 = W_self[67 * DOUT + col];
    float bi = bias[col];
    #pragma unroll
    for (int r = 0; r < 4; ++r) {
      int q = mt * 16 + fg * 4 + r;
      int row = T0C + q;
      uint4 sv = selidx[q];
      float agg = 0.f;
      #pragma unroll
      for (int s = 0; s < KK; ++s) {
        uint32_t wd = (s < 4) ? sv.x : (s < 8) ? sv.y : (s < 12) ? sv.z : sv.w;
        int j = (wd >> ((s & 3) * 8)) & 0xff;
        agg += msgs[j][col];
      }
      float v = acc2[ntl][r] + agg + bi
              + px[row] * ws0 + py[row] * ws1 + pz[row] * ws2 + rt[row] * ws3;
      v = fmaxf(v, 0.f);
      outp[((size_t)b * TAU + q) * DOUT + col] = v;
    }
  }
}

extern "C" void kernel_launch(void* const* d_in, const int* in_sizes, int n_in,
                              void* d_out, int out_size, void* d_ws, size_t ws_size,
                              hipStream_t stream) {
  (void)in_sizes; (void)n_in; (void)d_ws; (void)ws_size; (void)out_size;
  const float* x       = (const float*)d_in[0];
  const float* pos     = (const float*)d_in[1];
  const float* rot     = (const float*)d_in[2];
  const float* old_x   = (const float*)d_in[3];
  const float* old_pos = (const float*)d_in[4];
  const float* old_rot = (const float*)d_in[5];
  const float* W_self  = (const float*)d_in[6];
  const float* W_nbr   = (const float*)d_in[7];
  const float* bias    = (const float*)d_in[8];
  float* out = (float*)d_out;

  hipLaunchKernelGGL(navgcm_fused, dim3(NB), dim3(256), 0, stream,
                     x, pos, rot, old_x, old_pos, old_rot, W_self, W_nbr, bias, out);
}

// Round 6
// 45.925 us; speedup vs baseline: 8.9861x; 1.0935x over previous
//
#include <hip/hip_runtime.h>
#include <hip/hip_bf16.h>
#include <cstdint>
#include <cstddef>

#define NB 2048
#define TAU 32
#define T0C 96
#define LQ 128      // T0 + tau
#define DD 64
#define DOUT 64
#define KK 16

typedef unsigned long long u64;
typedef __attribute__((ext_vector_type(8))) short short8;
typedef __attribute__((ext_vector_type(4))) float f32x4;

#define KINV 1e30   // invalid-key sentinel (valid keys < 2^38)

// exact-rounding helpers: keep d2 bit-identical to the reference (no fma fusion)
__device__ __forceinline__ float fmul_exact(float a, float b) {
  float r; asm("v_mul_f32 %0, %1, %2" : "=v"(r) : "v"(a), "v"(b)); return r;
}
__device__ __forceinline__ float fadd_exact(float a, float b) {
  float r; asm("v_add_f32 %0, %1, %2" : "=v"(r) : "v"(a), "v"(b)); return r;
}
__device__ __forceinline__ unsigned short f2bf(float f) {
  __hip_bfloat16 h = __float2bfloat16(f);
  return *reinterpret_cast<unsigned short*>(&h);
}
__device__ __forceinline__ double shfl_xor_f64(double v, int mask) {
  u64 u = __double_as_longlong(v);
  int lo = __shfl_xor((int)(unsigned)(u & 0xffffffffULL), mask, 64);
  int hi = __shfl_xor((int)(unsigned)(u >> 32), mask, 64);
  return __longlong_as_double(((u64)(unsigned)hi << 32) | (unsigned)lo);
}

// compare-exchange: ascending (min to first) / descending (max to first)
#define CA(i, j) { double _lo = fmin(kd[i], kd[j]); double _hi = fmax(kd[i], kd[j]); kd[i] = _lo; kd[j] = _hi; }
#define CD(i, j) { double _lo = fmin(kd[i], kd[j]); double _hi = fmax(kd[i], kd[j]); kd[i] = _hi; kd[j] = _lo; }

// full bitonic sort of kd[0..15], ascending (static network, 80 CAS)
#define SORT16() do { \
  CA(0,1)  CD(2,3)  CA(4,5)  CD(6,7)  CA(8,9)  CD(10,11) CA(12,13) CD(14,15) \
  CA(0,2)  CA(1,3)  CD(4,6)  CD(5,7)  CA(8,10) CA(9,11)  CD(12,14) CD(13,15) \
  CA(0,1)  CA(2,3)  CD(4,5)  CD(6,7)  CA(8,9)  CA(10,11) CD(12,13) CD(14,15) \
  CA(0,4)  CA(1,5)  CA(2,6)  CA(3,7)  CD(8,12) CD(9,13)  CD(10,14) CD(11,15) \
  CA(0,2)  CA(1,3)  CA(4,6)  CA(5,7)  CD(8,10) CD(9,11)  CD(12,14) CD(13,15) \
  CA(0,1)  CA(2,3)  CA(4,5)  CA(6,7)  CD(8,9)  CD(10,11) CD(12,13) CD(14,15) \
  CA(0,8)  CA(1,9)  CA(2,10) CA(3,11) CA(4,12) CA(5,13)  CA(6,14)  CA(7,15)  \
  CA(0,4)  CA(1,5)  CA(2,6)  CA(3,7)  CA(8,12) CA(9,13)  CA(10,14) CA(11,15) \
  CA(0,2)  CA(1,3)  CA(4,6)  CA(5,7)  CA(8,10) CA(9,11)  CA(12,14) CA(13,15) \
  CA(0,1)  CA(2,3)  CA(4,5)  CA(6,7)  CA(8,9)  CA(10,11) CA(12,13) CA(14,15) \
} while (0)

// bitonic merge of a bitonic kd[0..15] -> ascending (4 stages, 32 CAS)
#define MERGE16() do { \
  CA(0,8)  CA(1,9)  CA(2,10) CA(3,11) CA(4,12) CA(5,13)  CA(6,14)  CA(7,15)  \
  CA(0,4)  CA(1,5)  CA(2,6)  CA(3,7)  CA(8,12) CA(9,13)  CA(10,14) CA(11,15) \
  CA(0,2)  CA(1,3)  CA(4,6)  CA(5,7)  CA(8,10) CA(9,11)  CA(12,14) CA(13,15) \
  CA(0,1)  CA(2,3)  CA(4,5)  CA(6,7)  CA(8,9)  CA(10,11) CA(12,13) CA(14,15) \
} while (0)

// merge sorted kd with partner lane's sorted list (xor mask), keep lowest 16
#define SHUF_MERGE(mask) do { \
  double pb[16]; \
  _Pragma("unroll") \
  for (int _i = 0; _i < 16; ++_i) pb[_i] = shfl_xor_f64(kd[15 - _i], mask); \
  _Pragma("unroll") \
  for (int _i = 0; _i < 16; ++_i) kd[_i] = fmin(kd[_i], pb[_i]); \
  MERGE16(); \
} while (0)

__global__ __launch_bounds__(256, 4) void navgcm_fused(
    const float* __restrict__ x, const float* __restrict__ pos_in, const float* __restrict__ rot_in,
    const float* __restrict__ old_x, const float* __restrict__ old_pos, const float* __restrict__ old_rot,
    const float* __restrict__ W_self, const float* __restrict__ W_nbr, const float* __restrict__ bias,
    float* __restrict__ outp)
{
  const int b = blockIdx.x;
  const int tid = threadIdx.x;
  const int lane = tid & 63;
  const int wv = tid >> 6;
  const int fr = lane & 15;   // MFMA fragment row/col within tile
  const int fg = lane >> 4;   // MFMA fragment k-group / row-group

  // union region: {Hs[128][72] + Wn[64][72] + Wsf[64][72]} (36864 B, phases A-C)
  //            <-> msgs f32[128][66] (33792 B, phases D-E)
  __shared__ __align__(16) unsigned char uni[36864];
  __shared__ float px[LQ], py[LQ], pz[LQ], rt[LQ];
  __shared__ uint4 selidx[32];

  unsigned short (*Hs)[72]  = reinterpret_cast<unsigned short(*)[72]>(uni);
  unsigned short (*Wn)[72]  = reinterpret_cast<unsigned short(*)[72]>(uni + 18432);
  unsigned short (*Wsf)[72] = reinterpret_cast<unsigned short(*)[72]>(uni + 27648);
  float (*msgs)[66] = reinterpret_cast<float(*)[66]>(uni);

  // ================= phase A: copy + stage =================
  float4* dnx = (float4*)(outp + (size_t)NB * TAU * DOUT);
  #pragma unroll
  for (int it = 0; it < 8; ++it) {
    int n = tid + 256 * it;              // [0,2048): row = n>>4, c4 = n&15
    int row = n >> 4, c4 = n & 15;
    const float4* src = (row < T0C)
        ? (const float4*)(old_x + ((size_t)b * LQ + row) * DD)
        : (const float4*)(x + ((size_t)b * TAU + (row - T0C)) * DD);
    float4 v = src[c4];
    dnx[(size_t)b * 2048 + n] = v;       // new_x
    ushort4 w4;
    w4.x = f2bf(v.x); w4.y = f2bf(v.y); w4.z = f2bf(v.z); w4.w = f2bf(v.w);
    *reinterpret_cast<ushort4*>(&Hs[row][c4 * 4]) = w4;
  }

  #pragma unroll
  for (int it = 0; it < 8; ++it) {
    int m = tid + 256 * it;              // n = m&63, kp = m>>6 in [0,32)
    int n = m & 63, kp = m >> 6;
    float a0 = W_nbr[(2 * kp) * DOUT + n], a1 = W_nbr[(2 * kp + 1) * DOUT + n];
    *reinterpret_cast<uint32_t*>(&Wn[n][2 * kp]) =
        (uint32_t)f2bf(a0) | ((uint32_t)f2bf(a1) << 16);
    float s0 = W_self[(2 * kp) * DOUT + n], s1 = W_self[(2 * kp + 1) * DOUT + n];
    *reinterpret_cast<uint32_t*>(&Wsf[n][2 * kp]) =
        (uint32_t)f2bf(s0) | ((uint32_t)f2bf(s1) << 16);
  }

  float* dpos = outp + (size_t)NB * TAU * DOUT + (size_t)NB * LQ * DD;
  float* drot = dpos + (size_t)NB * LQ * 3;
  if (tid < LQ) {
    int t = tid;
    float p0, p1, p2, rr;
    if (t < T0C) {
      const float* s = old_pos + ((size_t)b * LQ + t) * 3;
      p0 = s[0]; p1 = s[1]; p2 = s[2];
      rr = old_rot[(size_t)b * LQ + t];
    } else {
      const float* s = pos_in + ((size_t)b * TAU + (t - T0C)) * 3;
      p0 = s[0]; p1 = s[1]; p2 = s[2];
      rr = rot_in[(size_t)b * TAU + (t - T0C)];
    }
    px[t] = p0; py[t] = p1; pz[t] = p2; rt[t] = rr;
    size_t g = (size_t)b * LQ + t;
    dpos[g * 3 + 0] = p0; dpos[g * 3 + 1] = p1; dpos[g * 3 + 2] = p2;
    drot[g] = rr;
  }
  __syncthreads();   // b1: Hs/Wn/Wsf/pos ready

  // ========== phase B: selection, fully in registers + shuffles ==========
  // 8 threads/query; thread s8 scans j = 8c + s8 (interleaved -> broadcast
  // LDS reads). Key = d2bits*128 + j as f64 (exact; order == (d2,j) lex).
  {
    const int q = tid >> 3, s8 = tid & 7;
    const int i = T0C + q;
    const float pix = px[i], piy = py[i], piz = pz[i];
    double kd[16];
    #pragma unroll
    for (int c = 0; c < 16; ++c) {
      int j = 8 * c + s8;
      float dx = pix - px[j], dy = piy - py[j], dz = piz - pz[j];
      float d2 = fadd_exact(fadd_exact(fmul_exact(dx, dx), fmul_exact(dy, dy)),
                            fmul_exact(dz, dz));
      bool valid = (d2 <= 1.0f) && (j < i);
      double key = fma((double)__float_as_uint(d2), 128.0, (double)j);
      kd[c] = valid ? key : KINV;
    }
    SORT16();          // ascending per-thread sublist
    SHUF_MERGE(1);     // 8 -> 4 lists
    SHUF_MERGE(2);     // 4 -> 2
    SHUF_MERGE(4);     // 2 -> 1: all 8 lanes now hold the final sorted 16

    if (s8 == 0) {
      uint32_t w[4] = {0u, 0u, 0u, 0u};
      #pragma unroll
      for (int t = 0; t < KK; ++t) {
        double kv = kd[t];
        uint32_t jj;
        if (kv >= 1e29) {
          jj = 127u;                         // sentinel -> zero msg row
        } else {
          uint32_t d2b = (uint32_t)(kv * 0.0078125);       // trunc(kv/128)
          double rem = kv - 128.0 * (double)d2b;           // exact
          jj = (uint32_t)rem;
        }
        w[t >> 2] |= jj << ((t & 3) * 8);
      }
      uint4 sv; sv.x = w[0]; sv.y = w[1]; sv.z = w[2]; sv.w = w[3];
      selidx[q] = sv;
    }
  }

  // ================= phase C: msg MFMA (acc) =================
  short8 bW[4][2];
  #pragma unroll
  for (int nt = 0; nt < 4; ++nt)
    #pragma unroll
    for (int ks = 0; ks < 2; ++ks)
      bW[nt][ks] = *reinterpret_cast<const short8*>(&Wn[nt * 16 + fr][ks * 32 + fg * 8]);

  f32x4 acc[2][4];
  #pragma unroll
  for (int m = 0; m < 2; ++m)
    #pragma unroll
    for (int n = 0; n < 4; ++n)
      acc[m][n] = (f32x4){0.f, 0.f, 0.f, 0.f};

  #pragma unroll
  for (int mtl = 0; mtl < 2; ++mtl) {
    int mrow = (2 * wv + mtl) * 16;
    short8 a0 = *reinterpret_cast<const short8*>(&Hs[mrow + fr][fg * 8]);
    short8 a1 = *reinterpret_cast<const short8*>(&Hs[mrow + fr][32 + fg * 8]);
    #pragma unroll
    for (int nt = 0; nt < 4; ++nt) {
      acc[mtl][nt] = __builtin_amdgcn_mfma_f32_16x16x32_bf16(a0, bW[nt][0], acc[mtl][nt], 0, 0, 0);
      acc[mtl][nt] = __builtin_amdgcn_mfma_f32_16x16x32_bf16(a1, bW[nt][1], acc[mtl][nt], 0, 0, 0);
    }
  }

  // self-term MFMA (registers only)
  const int mt = wv & 1;
  const int ntb = (wv >> 1) * 2;
  short8 aQ0 = *reinterpret_cast<const short8*>(&Hs[T0C + mt * 16 + fr][fg * 8]);
  short8 aQ1 = *reinterpret_cast<const short8*>(&Hs[T0C + mt * 16 + fr][32 + fg * 8]);
  f32x4 acc2[2];
  #pragma unroll
  for (int n = 0; n < 2; ++n) acc2[n] = (f32x4){0.f, 0.f, 0.f, 0.f};
  #pragma unroll
  for (int ntl = 0; ntl < 2; ++ntl) {
    int nt = ntb + ntl;
    short8 b0 = *reinterpret_cast<const short8*>(&Wsf[nt * 16 + fr][fg * 8]);
    short8 b1 = *reinterpret_cast<const short8*>(&Wsf[nt * 16 + fr][32 + fg * 8]);
    acc2[ntl] = __builtin_amdgcn_mfma_f32_16x16x32_bf16(aQ0, b0, acc2[ntl], 0, 0, 0);
    acc2[ntl] = __builtin_amdgcn_mfma_f32_16x16x32_bf16(aQ1, b1, acc2[ntl], 0, 0, 0);
  }
  __syncthreads();   // b2: all Hs/Wn/Wsf reads done -> union reusable as msgs

  // ================= phase D: msgs = acc + pos-terms -> LDS =================
  float wn4[4][4];
  #pragma unroll
  for (int nt = 0; nt < 4; ++nt) {
    int col = nt * 16 + fr;
    wn4[nt][0] = W_nbr[64 * DOUT + col];
    wn4[nt][1] = W_nbr[65 * DOUT + col];
    wn4[nt][2] = W_nbr[66 * DOUT + col];
    wn4[nt][3] = W_nbr[67 * DOUT + col];
  }
  #pragma unroll
  for (int mtl = 0; mtl < 2; ++mtl) {
    #pragma unroll
    for (int r = 0; r < 4; ++r) {
      int row = (2 * wv + mtl) * 16 + fg * 4 + r;   // C/D: row=(lane>>4)*4+reg
      float p0 = px[row], p1 = py[row], p2 = pz[row], p3 = rt[row];
      #pragma unroll
      for (int nt = 0; nt < 4; ++nt) {
        float v = acc[mtl][nt][r]
                + p0 * wn4[nt][0] + p1 * wn4[nt][1] + p2 * wn4[nt][2] + p3 * wn4[nt][3];
        msgs[row][nt * 16 + fr] = (row == LQ - 1) ? 0.f : v;  // row 127 = sentinel sink
      }
    }
  }
  __syncthreads();   // b3: msgs + selidx ready

  // ================= phase E: gather + epilogue =================
  #pragma unroll
  for (int ntl = 0; ntl < 2; ++ntl) {
    int col = (ntb + ntl) * 16 + fr;
    float ws0 = W_self[64 * DOUT + col], ws1 = W_self[65 * DOUT + col];
    float ws2 = W_self[66 * DOUT + col], ws3 = W_self[67 * DOUT + col];
    float bi = bias[col];
    #pragma unroll
    for (int r = 0; r < 4; ++r) {
      int q = mt * 16 + fg * 4 + r;
      int row = T0C + q;
      uint4 sv = selidx[q];
      float agg = 0.f;
      #pragma unroll
      for (int s = 0; s < KK; ++s) {
        uint32_t wd = (s < 4) ? sv.x : (s < 8) ? sv.y : (s < 12) ? sv.z : sv.w;
        int j = (wd >> ((s & 3) * 8)) & 0xff;
        agg += msgs[j][col];
      }
      float v = acc2[ntl][r] + agg + bi
              + px[row] * ws0 + py[row] * ws1 + pz[row] * ws2 + rt[row] * ws3;
      v = fmaxf(v, 0.f);
      outp[((size_t)b * TAU + q) * DOUT + col] = v;
    }
  }
}

extern "C" void kernel_launch(void* const* d_in, const int* in_sizes, int n_in,
                              void* d_out, int out_size, void* d_ws, size_t ws_size,
                              hipStream_t stream) {
  (void)in_sizes; (void)n_in; (void)d_ws; (void)ws_size; (void)out_size;
  const float* x       = (const float*)d_in[0];
  const float* pos     = (const float*)d_in[1];
  const float* rot     = (const float*)d_in[2];
  const float* old_x   = (const float*)d_in[3];
  const float* old_pos = (const float*)d_in[4];
  const float* old_rot = (const float*)d_in[5];
  const float* W_self  = (const float*)d_in[6];
  const float* W_nbr   = (const float*)d_in[7];
  const float* bias    = (const float*)d_in[8];
  float* out = (float*)d_out;

  hipLaunchKernelGGL(navgcm_fused, dim3(NB), dim3(256), 0, stream,
                     x, pos, rot, old_x, old_pos, old_rot, W_self, W_nbr, bias, out);
}